// Round 13
// baseline (222.254 us; speedup 1.0000x reference)
//
#include <hip/hip_runtime.h>
#include <stdint.h>

typedef unsigned int u32;
typedef unsigned long long u64;
typedef int v4i  __attribute__((ext_vector_type(4)));
typedef int v16i __attribute__((ext_vector_type(16)));

#define K_MSG   1024
#define N_CODE  2048
#define NB      32768

// ------------- pack G -> fragment-major i8 B (proven round 10/11/12) --------
// BF tile = one MFMA B-fragment (32 cols x 32 k) = 1024 B in LANE order:
// a wave's frag load is base + lane*16 -> one fully-coalesced dwordx4.
__global__ void pack_gBF(const int* __restrict__ G, u32* __restrict__ bf) {
    int idx = blockIdx.x * blockDim.x + threadIdx.x;   // 524288
    const int j  = idx & (N_CODE - 1);                 // coalesced G reads
    const int kq = idx >> 11;                          // dword of k: 0..255
    u32 p = 0;
#pragma unroll
    for (int i = 0; i < 4; ++i) {
        int v = G[(size_t)(kq * 4 + i) * N_CODE + j];
        p |= (u32)(v & 1) << (8 * i);
    }
    const int jb = j >> 5, jr = j & 31;
    const int kb = kq >> 3, hi = (kq >> 2) & 1, b4 = kq & 3;
    bf[(size_t)(jb * 32 + kb) * 256 + hi * 128 + jr * 4 + b4] = p;
}

// ---------------- GEMM -> bit-packed output ---------------------------------
// Round-10 chassis: 2048 blocks, XCD swizzle, block = 64-row M-panel x 512 cols,
// wave tile 64x128, barrier-free 32-step k-loop, 4-deep named pipeline.
// Changes: (1) stage packs b (int32) -> i8 LDS directly (pack_bi8 fused away);
// (2) epilogue ballot-packs parity bits -> 8.4 MB instead of 268 MB stores.

#define MFMA_I8(va, vb, vc) __builtin_amdgcn_mfma_i32_32x32x32_i8(va, vb, vc, 0, 0, 0)

#define MFMA_SET(sfx) do {                              \
    acc[0][0] = MFMA_I8(a0##sfx, b0##sfx, acc[0][0]);   \
    acc[0][1] = MFMA_I8(a0##sfx, b1##sfx, acc[0][1]);   \
    acc[0][2] = MFMA_I8(a0##sfx, b2##sfx, acc[0][2]);   \
    acc[0][3] = MFMA_I8(a0##sfx, b3##sfx, acc[0][3]);   \
    acc[1][0] = MFMA_I8(a1##sfx, b0##sfx, acc[1][0]);   \
    acc[1][1] = MFMA_I8(a1##sfx, b1##sfx, acc[1][1]);   \
    acc[1][2] = MFMA_I8(a1##sfx, b2##sfx, acc[1][2]);   \
    acc[1][3] = MFMA_I8(a1##sfx, b3##sfx, acc[1][3]);   \
} while (0)

#define LOAD_SET(sfx, s_) do {                                      \
    int ao_ = lr * 1024 + ((((s_) * 32) + hi * 16) ^ axor);         \
    a0##sfx = *(const v4i*)(As + ao_);                              \
    a1##sfx = *(const v4i*)(As + ao_ + 32768);                      \
    b0##sfx = *(const v4i*)(bp0 + (size_t)(s_) * 1024);             \
    b1##sfx = *(const v4i*)(bp1 + (size_t)(s_) * 1024);             \
    b2##sfx = *(const v4i*)(bp2 + (size_t)(s_) * 1024);             \
    b3##sfx = *(const v4i*)(bp3 + (size_t)(s_) * 1024);             \
} while (0)

__global__ __launch_bounds__(256, 2) void gemm_i8(const int* __restrict__ b,
                                                  const char* __restrict__ bf,
                                                  u32* __restrict__ pk) {
    __shared__ __align__(16) char As[64 * 1024];    // 64 KB

    const int t   = threadIdx.x;
    // bijective XCD swizzle (2048 % 8 == 0): XCD k owns disjoint M-panels.
    const int bid = blockIdx.x;
    const int swz = (bid & 7) * 256 + (bid >> 3);
    const int m0  = (swz >> 2) * 64;
    const int n0  = (swz & 3) * 512;

    const int w = t >> 6, lane = t & 63, lr = lane & 31, hi = lane >> 5;
    const int axor = (lr & 7) << 4;

    // ---- stage: pack own b-panel (64 x 1024 int32 -> i8) into swizzled LDS.
    // Row i, bytes t*4..t*4+3; byte B of row R stored at B ^ ((R&7)<<4)
    // (identical convention to LOAD_SET's read; proven absmax=0 in round 12).
    {
        const int* src = b + (size_t)m0 * K_MSG;
#pragma unroll 8
        for (int i = 0; i < 64; ++i) {
            int4 v = *(const int4*)(src + (size_t)i * K_MSG + t * 4); // coalesced
            u32 p = (u32)(v.x & 1) | ((u32)(v.y & 1) << 8) |
                    ((u32)(v.z & 1) << 16) | ((u32)(v.w & 1) << 24);
            *(u32*)(As + i * 1024 + ((t * 4) ^ ((i & 7) << 4))) = p;
        }
    }
    __syncthreads();    // the only barrier

    // fragment-major B bases: colblk = n0/32 + w*4 + ni, frag stride 32KB
    const char* bp0 = bf + ((size_t)(n0 >> 5) + w * 4) * 32768 + lane * 16;
    const char* bp1 = bp0 + 32768;
    const char* bp2 = bp0 + 65536;
    const char* bp3 = bp0 + 98304;

    v16i acc[2][4] = {};
    v4i a0A, a1A, b0A, b1A, b2A, b3A;
    v4i a0B, a1B, b0B, b1B, b2B, b3B;
    v4i a0C, a1C, b0C, b1C, b2C, b3C;
    v4i a0D, a1D, b0D, b1D, b2D, b3D;

    LOAD_SET(A, 0);
    LOAD_SET(B, 1);
#pragma unroll 1
    for (int s = 0; s < 32; s += 4) {
        LOAD_SET(C, s + 2);
        LOAD_SET(D, s + 3);
        MFMA_SET(A);
        MFMA_SET(B);
        if (s + 4 < 32) {
            LOAD_SET(A, s + 4);
            LOAD_SET(B, s + 5);
        }
        MFMA_SET(C);
        MFMA_SET(D);
    }

    // ---- epilogue: ballot-pack parity bits. For frag (mi,ni), reg r:
    // pred over the wave = rows {row0 (hi=0), row0+4 (hi=1)} x cols lr.
    // ballot low32 = row0, high32 = row0+4 (cols cb*32..cb*32+31).
#pragma unroll
    for (int mi = 0; mi < 2; ++mi) {
#pragma unroll
        for (int ni = 0; ni < 4; ++ni) {
            const int cb = (n0 >> 5) + w * 4 + ni;
#pragma unroll
            for (int r = 0; r < 16; ++r) {
                u64 m = __ballot((acc[mi][ni][r] & 1) != 0);
                if (lane == r) {
                    const int row0 = m0 + mi * 32 + (r & 3) + 8 * (r >> 2);
                    pk[(size_t)row0 * 64 + cb]       = (u32)m;
                    pk[(size_t)(row0 + 4) * 64 + cb] = (u32)(m >> 32);
                }
            }
        }
    }
}

// ---------------- expand: packed bits -> int32 output (stream-rate) ---------
__global__ void expand_bits(const u32* __restrict__ pk, int* __restrict__ out) {
    const int idx = blockIdx.x * blockDim.x + threadIdx.x;   // 2M words
    const u32 p = pk[idx];
    int4* dst = (int4*)(out + (size_t)idx * 32);
#pragma unroll
    for (int q = 0; q < 8; ++q) {
        int4 v;
        v.x = (int)((p >> (4 * q))     & 1u);
        v.y = (int)((p >> (4 * q + 1)) & 1u);
        v.z = (int)((p >> (4 * q + 2)) & 1u);
        v.w = (int)((p >> (4 * q + 3)) & 1u);
        dst[q] = v;
    }
}

// ---------------- fallback (only if ws too small) ---------------------------
__global__ void encode_naive(const int* __restrict__ b, const int* __restrict__ G,
                             int* __restrict__ out) {
    size_t idx = (size_t)blockIdx.x * blockDim.x + threadIdx.x;
    size_t total = (size_t)NB * N_CODE;
    if (idx >= total) return;
    int i = (int)(idx / N_CODE);
    int j = (int)(idx % N_CODE);
    int acc = 0;
    for (int k = 0; k < K_MSG; ++k)
        acc ^= b[(size_t)i * K_MSG + k] & G[(size_t)k * N_CODE + j];
    out[idx] = acc & 1;
}

extern "C" void kernel_launch(void* const* d_in, const int* in_sizes, int n_in,
                              void* d_out, int out_size, void* d_ws, size_t ws_size,
                              hipStream_t stream) {
    const int* b = (const int*)d_in[0];
    const int* G = (const int*)d_in[1];
    int* out = (int*)d_out;

    const size_t bf_bytes = (size_t)N_CODE * K_MSG;            // 2 MiB
    const size_t pk_bytes = (size_t)NB * (N_CODE / 8);         // 8 MiB

    if (ws_size < bf_bytes + pk_bytes) {
        size_t total = (size_t)NB * N_CODE;
        encode_naive<<<(unsigned)((total + 255) / 256), 256, 0, stream>>>(b, G, out);
        return;
    }

    char* bf = (char*)d_ws;
    u32*  pk = (u32*)((char*)d_ws + bf_bytes);

    pack_gBF<<<2048, 256, 0, stream>>>(G, (u32*)bf);
    gemm_i8<<<2048, 256, 0, stream>>>(b, bf, pk);              // 512 M-panels x 4 N
    expand_bits<<<(NB * N_CODE / 32) / 256, 256, 0, stream>>>(pk, out);
}

// Round 14
// 138.885 us; speedup vs baseline: 1.6003x; 1.6003x over previous
//
#include <hip/hip_runtime.h>
#include <stdint.h>

typedef unsigned int u32;
typedef unsigned long long u64;
typedef int v4i  __attribute__((ext_vector_type(4)));
typedef int v16i __attribute__((ext_vector_type(16)));

#define K_MSG   1024
#define N_CODE  2048
#define NB      32768

// ------------- pack G -> fragment-major i8 B (proven round 10-13) -----------
__global__ void pack_gBF(const int* __restrict__ G, u32* __restrict__ bf) {
    int idx = blockIdx.x * blockDim.x + threadIdx.x;   // 524288
    const int j  = idx & (N_CODE - 1);                 // coalesced G reads
    const int kq = idx >> 11;                          // dword of k: 0..255
    u32 p = 0;
#pragma unroll
    for (int i = 0; i < 4; ++i) {
        int v = G[(size_t)(kq * 4 + i) * N_CODE + j];
        p |= (u32)(v & 1) << (8 * i);
    }
    const int jb = j >> 5, jr = j & 31;
    const int kb = kq >> 3, hi = (kq >> 2) & 1, b4 = kq & 3;
    bf[(size_t)(jb * 32 + kb) * 256 + hi * 128 + jr * 4 + b4] = p;
}

// ---------------- all-in-one GEMM -------------------------------------------
// 512 blocks, 1 block per 64-row M-panel (b packed ONCE into LDS), 4 N-passes
// of 512 cols. Per pass: round-10 k-loop (wave tile 64x128, 4-deep pipeline,
// fragment-major B from L2) -> ballot-pack parity to pk_lds (double-buffered)
// -> sync -> coalesced expand: per row two 1KB-contiguous dwordx4 store instrs.

#define MFMA_I8(va, vb, vc) __builtin_amdgcn_mfma_i32_32x32x32_i8(va, vb, vc, 0, 0, 0)

#define MFMA_SET(sfx) do {                              \
    acc[0][0] = MFMA_I8(a0##sfx, b0##sfx, acc[0][0]);   \
    acc[0][1] = MFMA_I8(a0##sfx, b1##sfx, acc[0][1]);   \
    acc[0][2] = MFMA_I8(a0##sfx, b2##sfx, acc[0][2]);   \
    acc[0][3] = MFMA_I8(a0##sfx, b3##sfx, acc[0][3]);   \
    acc[1][0] = MFMA_I8(a1##sfx, b0##sfx, acc[1][0]);   \
    acc[1][1] = MFMA_I8(a1##sfx, b1##sfx, acc[1][1]);   \
    acc[1][2] = MFMA_I8(a1##sfx, b2##sfx, acc[1][2]);   \
    acc[1][3] = MFMA_I8(a1##sfx, b3##sfx, acc[1][3]);   \
} while (0)

#define LOAD_SET(sfx, s_) do {                                      \
    int ao_ = lr * 1024 + ((((s_) * 32) + hi * 16) ^ axor);         \
    a0##sfx = *(const v4i*)(As + ao_);                              \
    a1##sfx = *(const v4i*)(As + ao_ + 32768);                      \
    b0##sfx = *(const v4i*)(bp0 + (size_t)(s_) * 1024);             \
    b1##sfx = *(const v4i*)(bp1 + (size_t)(s_) * 1024);             \
    b2##sfx = *(const v4i*)(bp2 + (size_t)(s_) * 1024);             \
    b3##sfx = *(const v4i*)(bp3 + (size_t)(s_) * 1024);             \
} while (0)

__global__ __launch_bounds__(256, 2) void gemm_all(const int* __restrict__ b,
                                                   const char* __restrict__ bf,
                                                   int* __restrict__ out) {
    __shared__ __align__(16) char As[64 * 1024];      // 64 KB packed b-panel
    __shared__ u32 pk[2][64 * 16];                    // 2 x 4 KB parity bits

    const int t   = threadIdx.x;
    // bijective XCD swizzle (512 % 8 == 0): XCD k owns contiguous M-panels.
    const int bid = blockIdx.x;
    const int m0  = ((bid & 7) * 64 + (bid >> 3)) * 64;

    const int w = t >> 6, lane = t & 63, lr = lane & 31, hi = lane >> 5;
    const int axor = (lr & 7) << 4;

    // ---- stage: pack own b-panel (64 x 1024 int32 -> i8) into swizzled LDS
    // (proven absmax=0 in rounds 12/13). b read from HBM exactly once.
    {
        const int* src = b + (size_t)m0 * K_MSG;
#pragma unroll 8
        for (int i = 0; i < 64; ++i) {
            int4 v = *(const int4*)(src + (size_t)i * K_MSG + t * 4); // coalesced
            u32 p = (u32)(v.x & 1) | ((u32)(v.y & 1) << 8) |
                    ((u32)(v.z & 1) << 16) | ((u32)(v.w & 1) << 24);
            *(u32*)(As + i * 1024 + ((t * 4) ^ ((i & 7) << 4))) = p;
        }
    }
    __syncthreads();

#pragma unroll 1
    for (int pass = 0; pass < 4; ++pass) {
        const int cur = pass & 1;
        // fragment-major B bases: colblk = pass*16 + w*4 + ni, frag stride 32KB
        const char* bp0 = bf + ((size_t)pass * 16 + w * 4) * 32768 + lane * 16;
        const char* bp1 = bp0 + 32768;
        const char* bp2 = bp0 + 65536;
        const char* bp3 = bp0 + 98304;

        v16i acc[2][4] = {};
        v4i a0A, a1A, b0A, b1A, b2A, b3A;
        v4i a0B, a1B, b0B, b1B, b2B, b3B;
        v4i a0C, a1C, b0C, b1C, b2C, b3C;
        v4i a0D, a1D, b0D, b1D, b2D, b3D;

        LOAD_SET(A, 0);
        LOAD_SET(B, 1);
#pragma unroll 1
        for (int s = 0; s < 32; s += 4) {
            LOAD_SET(C, s + 2);
            LOAD_SET(D, s + 3);
            MFMA_SET(A);
            MFMA_SET(B);
            if (s + 4 < 32) {
                LOAD_SET(A, s + 4);
                LOAD_SET(B, s + 5);
            }
            MFMA_SET(C);
            MFMA_SET(D);
        }

        // ---- ballot-pack parity into pk_lds (bit i of ballot = lane i):
        // low 32 = cols 0-31 @ row0 (hi=0 lanes), high 32 = row0+4 (hi=1).
#pragma unroll
        for (int mi = 0; mi < 2; ++mi) {
#pragma unroll
            for (int ni = 0; ni < 4; ++ni) {
                const int cbL = w * 4 + ni;          // 32-col block within pass
#pragma unroll
                for (int r = 0; r < 16; ++r) {
                    u64 m = __ballot((acc[mi][ni][r] & 1) != 0);
                    if ((lane & 31) == r) {
                        const int row = mi * 32 + (r & 3) + 8 * (r >> 2) + 4 * hi;
                        pk[cur][row * 16 + cbL] = (u32)(m >> (hi * 32));
                    }
                }
            }
        }
        __syncthreads();   // pk[cur] complete; pk[cur^1] free (proven by barrier chain)

        // ---- expand: wave w owns rows w*16..+15; per row two 1KB-contiguous
        // dwordx4 store instructions (fill-kernel pattern).
        int* op = out + (size_t)m0 * N_CODE + pass * 512;
#pragma unroll 1
        for (int rr = 0; rr < 16; ++rr) {
            const int row = w * 16 + rr;
            const int sb  = (lane & 7) * 4;
            u32 p0 = pk[cur][row * 16 + (lane >> 3)];       // cols 0..255
            u32 p1 = pk[cur][row * 16 + 8 + (lane >> 3)];   // cols 256..511
            v4i v0, v1;
            v0.x = (int)((p0 >> (sb + 0)) & 1u);
            v0.y = (int)((p0 >> (sb + 1)) & 1u);
            v0.z = (int)((p0 >> (sb + 2)) & 1u);
            v0.w = (int)((p0 >> (sb + 3)) & 1u);
            v1.x = (int)((p1 >> (sb + 0)) & 1u);
            v1.y = (int)((p1 >> (sb + 1)) & 1u);
            v1.z = (int)((p1 >> (sb + 2)) & 1u);
            v1.w = (int)((p1 >> (sb + 3)) & 1u);
            int* dst = op + (size_t)row * N_CODE + lane * 4;
            *(v4i*)dst         = v0;    // lanes: bytes [0,1KB) contiguous
            *(v4i*)(dst + 256) = v1;    // lanes: bytes [1KB,2KB) contiguous
        }
    }
}

// ---------------- fallback (only if ws too small) ---------------------------
__global__ void encode_naive(const int* __restrict__ b, const int* __restrict__ G,
                             int* __restrict__ out) {
    size_t idx = (size_t)blockIdx.x * blockDim.x + threadIdx.x;
    size_t total = (size_t)NB * N_CODE;
    if (idx >= total) return;
    int i = (int)(idx / N_CODE);
    int j = (int)(idx % N_CODE);
    int acc = 0;
    for (int k = 0; k < K_MSG; ++k)
        acc ^= b[(size_t)i * K_MSG + k] & G[(size_t)k * N_CODE + j];
    out[idx] = acc & 1;
}

extern "C" void kernel_launch(void* const* d_in, const int* in_sizes, int n_in,
                              void* d_out, int out_size, void* d_ws, size_t ws_size,
                              hipStream_t stream) {
    const int* b = (const int*)d_in[0];
    const int* G = (const int*)d_in[1];
    int* out = (int*)d_out;

    const size_t bf_bytes = (size_t)N_CODE * K_MSG;      // 2 MiB

    if (ws_size < bf_bytes) {
        size_t total = (size_t)NB * N_CODE;
        encode_naive<<<(unsigned)((total + 255) / 256), 256, 0, stream>>>(b, G, out);
        return;
    }

    char* bf = (char*)d_ws;

    pack_gBF<<<2048, 256, 0, stream>>>(G, (u32*)bf);
    gemm_all<<<NB / 64, 256, 0, stream>>>(b, bf, out);   // 512 blocks
}